// Round 13
// baseline (336.574 us; speedup 1.0000x reference)
//
#include <hip/hip_runtime.h>

#define HW 65536
#define NOUT 81     // 9 mask + 4*18 off
#define NFEAT 192   // 144 patch + 48 passthrough
#define WROW 84     // padded weight row stride

typedef unsigned short ushort_t;
typedef unsigned int uint_t;

__device__ __forceinline__ float bfhi(uint_t u) {   // high ushort IS the f32 pattern
    union { unsigned int i; float f; } v; v.i = u & 0xffff0000u; return v.f;
}
__device__ __forceinline__ float bflo(uint_t u) {
    union { unsigned int i; float f; } v; v.i = u << 16; return v.f;
}
__device__ __forceinline__ ushort_t f2bf(float f) {
    union { float f; unsigned int i; } v; v.f = f;
    unsigned int r = v.i + 0x7FFF + ((v.i >> 16) & 1);   // RNE
    return (ushort_t)(r >> 16);
}

// ---------------------------------------------------------------------------
// Setup: collapse (conv3x3 -> 1x1) into a single 192->81 linear map, padded.
// ---------------------------------------------------------------------------
__global__ __launch_bounds__(256) void setup_weights(
    const float* __restrict__ off_pconv_w,  // (4,16,16,3,3)
    const float* __restrict__ off_w,        // (4,18,64)
    const float* __restrict__ off_b,        // (4,18)
    const float* __restrict__ mask_pconv_w, // (16,16,3,3)
    const float* __restrict__ mask_w,       // (9,64)
    const float* __restrict__ mask_b,       // (9,)
    float* __restrict__ WtP,                // (192,84)
    float* __restrict__ biasP)              // (81,)
{
    int id = blockIdx.x * 256 + threadIdx.x;
    const float PTS[18] = {-1,-1, -1,0, -1,1, 0,-1, 0,0, 0,1, 1,-1, 1,0, 1,1};
    if (id < NFEAT * WROW) {
        int f = id / WROW;
        int o = id % WROW;
        float v = 0.f;
        if (o < NOUT) {
            if (f < 144) {
                int p = f >> 4, c = f & 15;
                float s = 0.f;
                if (o < 9) {
                    for (int cm = 0; cm < 16; ++cm)
                        s += mask_w[o * 64 + cm] * mask_pconv_w[(cm * 16 + c) * 9 + p];
                } else {
                    int oo = o - 9, i = oo / 18, j = oo % 18;
                    for (int cm = 0; cm < 16; ++cm)
                        s += off_w[(i * 18 + j) * 64 + cm] * off_pconv_w[((i * 16 + cm) * 16 + c) * 9 + p];
                }
                v = s;
            } else {
                int c = f - 144;
                if (o < 9) v = mask_w[o * 64 + 16 + c];
                else { int oo = o - 9, i = oo / 18, j = oo % 18; v = off_w[(i * 18 + j) * 64 + 16 + c]; }
            }
        }
        WtP[id] = v;
    } else if (id < NFEAT * WROW + NOUT) {
        int o = id - NFEAT * WROW;
        float v;
        if (o < 9) v = mask_b[o];
        else {
            int oo = o - 9, i = oo / 18, j = oo % 18;
            v = off_b[i * 18 + j] + PTS[j] * (float)(2 * i + 1);
        }
        biasP[o] = v;
    }
}

// 84 FMAs: 21-output weight slice applied to 4 pixels' x values.
#define FMA21X4(X0, X1, X2, X3, WR) do {                                   \
    _Pragma("unroll")                                                      \
    for (int j5 = 0; j5 < 5; ++j5) {                                       \
        float4 w4 = *(const float4*)((WR) + 4 * j5);                       \
        acc0[4*j5+0] = fmaf(X0, w4.x, acc0[4*j5+0]);                       \
        acc0[4*j5+1] = fmaf(X0, w4.y, acc0[4*j5+1]);                       \
        acc0[4*j5+2] = fmaf(X0, w4.z, acc0[4*j5+2]);                       \
        acc0[4*j5+3] = fmaf(X0, w4.w, acc0[4*j5+3]);                       \
        acc1[4*j5+0] = fmaf(X1, w4.x, acc1[4*j5+0]);                       \
        acc1[4*j5+1] = fmaf(X1, w4.y, acc1[4*j5+1]);                       \
        acc1[4*j5+2] = fmaf(X1, w4.z, acc1[4*j5+2]);                       \
        acc1[4*j5+3] = fmaf(X1, w4.w, acc1[4*j5+3]);                       \
        acc2[4*j5+0] = fmaf(X2, w4.x, acc2[4*j5+0]);                       \
        acc2[4*j5+1] = fmaf(X2, w4.y, acc2[4*j5+1]);                       \
        acc2[4*j5+2] = fmaf(X2, w4.z, acc2[4*j5+2]);                       \
        acc2[4*j5+3] = fmaf(X2, w4.w, acc2[4*j5+3]);                       \
        acc3[4*j5+0] = fmaf(X3, w4.x, acc3[4*j5+0]);                       \
        acc3[4*j5+1] = fmaf(X3, w4.y, acc3[4*j5+1]);                       \
        acc3[4*j5+2] = fmaf(X3, w4.z, acc3[4*j5+2]);                       \
        acc3[4*j5+3] = fmaf(X3, w4.w, acc3[4*j5+3]);                       \
    }                                                                      \
    {                                                                      \
        float w20 = (WR)[20];                                              \
        acc0[20] = fmaf(X0, w20, acc0[20]);                                \
        acc1[20] = fmaf(X1, w20, acc1[20]);                                \
        acc2[20] = fmaf(X2, w20, acc2[20]);                                \
        acc3[20] = fmaf(X3, w20, acc3[20]);                                \
    }                                                                      \
} while (0)

// ---------------------------------------------------------------------------
// MERGED conv + transpose dispatch: conv blocks (VALU-bound) at every 5th
// blockIdx interleave with transpose blocks (BW-bound) so the two phases
// overlap on each CU (separate pipes ~ max, not sum).
//   bid % 5 == 4 -> conv block   cix = bid/5        (512 blocks)
//   else         -> transpose    tix = bid - bid/5  (2048 blocks)
// ---------------------------------------------------------------------------
__global__ __launch_bounds__(256, 2) void conv_and_transpose(
    const float* __restrict__ x,     // (2,64,HW)
    const float* __restrict__ WtP,   // (192,84)
    const float* __restrict__ biasP, // (81,)
    const float* __restrict__ y,     // (4,64,HW)
    float* __restrict__ mask_ws,     // (2,9,HW)
    float* __restrict__ off_ws,      // (2,72,HW)
    ushort_t* __restrict__ Tc)       // (8,HW,32) bf16 c4-major
{
    __shared__ float wl[NFEAT * WROW];    // 64.5 KB (conv blocks only)
    int bid = blockIdx.x;
    int tid = threadIdx.x;

    if (bid % 5 == 4) {
        // ================= conv block =================
        int cix = bid / 5;               // 0..511
        {
            const float4* src = (const float4*)WtP;
            float4* dst = (float4*)wl;
            for (int idx = tid; idx < NFEAT * WROW / 4; idx += 256) dst[idx] = src[idx];
        }
        __syncthreads();

        int c4 = tid & 3, grp = tid >> 2;
        int b = cix >> 8, h = cix & 255;
        int wbase = grp * 4;
        int pix0 = h * 256 + wbase;
        int ob0 = c4 * 20;

        float acc0[21], acc1[21], acc2[21], acc3[21];
#pragma unroll
        for (int j = 0; j < 21; ++j) {
            float bj = biasP[ob0 + j];
            acc0[j] = bj; acc1[j] = bj; acc2[j] = bj; acc3[j] = bj;
        }

        const float* xb = x + (size_t)b * 64 * HW;

#pragma unroll 1
        for (int r = 0; r < 3; ++r) {
            int hh = h + r - 1;
            bool vrow = ((unsigned)hh < 256u);
            int rbase = hh * 256 + wbase;
#pragma unroll 1
            for (int c = 0; c < 16; ++c) {
                const float* xr = xb + c * HW + rbase;
                float4 x4 = vrow ? *(const float4*)xr : make_float4(0.f, 0.f, 0.f, 0.f);
                float xm1 = (vrow && wbase > 0)       ? xr[-1] : 0.f;
                float xp4 = (vrow && wbase + 4 < 256) ? xr[4]  : 0.f;
                const float* wr0 = wl + ((r * 3 + 0) * 16 + c) * WROW + ob0;
                const float* wr1 = wl + ((r * 3 + 1) * 16 + c) * WROW + ob0;
                const float* wr2 = wl + ((r * 3 + 2) * 16 + c) * WROW + ob0;
                FMA21X4(xm1, x4.x, x4.y, x4.z, wr0);
                FMA21X4(x4.x, x4.y, x4.z, x4.w, wr1);
                FMA21X4(x4.y, x4.z, x4.w, xp4, wr2);
            }
        }
#pragma unroll 1
        for (int c = 0; c < 48; ++c) {
            float4 x4 = *(const float4*)(xb + (16 + c) * HW + pix0);
            const float* wr = wl + (144 + c) * WROW + ob0;
            FMA21X4(x4.x, x4.y, x4.z, x4.w, wr);
        }

#pragma unroll
        for (int j = 0; j < 21; ++j) {
            int o = ob0 + j;
            float* pl;
            if (o < 9) pl = mask_ws + (size_t)(b * 9 + o) * HW + pix0;
            else       pl = off_ws  + (size_t)(b * 72 + (o - 9)) * HW + pix0;
            pl[0] = acc0[j];
            pl[1] = acc1[j];
            pl[2] = acc2[j];
            pl[3] = acc3[j];
        }
    } else {
        // ================= transpose block =================
        int tix = bid - bid / 5;         // 0..2047
        int z = tix & 7, pr = tix >> 3;
        int pix = pr * 256 + tid;
        int xb = z >> 2, i = z & 3;

        const float* p0 = y + (size_t)(xb * 64 + i * 16) * HW + pix;
        const float* p1 = y + (size_t)((xb + 2) * 64 + i * 16) * HW + pix;

        ushort_t v0[16], v1[16];
#pragma unroll
        for (int c = 0; c < 16; ++c) v0[c] = f2bf(p0[(size_t)c * HW]);
#pragma unroll
        for (int c = 0; c < 16; ++c) v1[c] = f2bf(p1[(size_t)c * HW]);

        uint4* dst = (uint4*)(Tc + ((size_t)z * HW + pix) * 32);
#pragma unroll
        for (int j = 0; j < 4; ++j) {
            ushort_t row[8] = {v0[4*j], v0[4*j+1], v0[4*j+2], v0[4*j+3],
                               v1[4*j], v1[4*j+1], v1[4*j+2], v1[4*j+3]};
            dst[j] = *(const uint4*)row;
        }
    }
}

// ---------------------------------------------------------------------------
// Warp kernel v8: as v7 but k-loop unrolled 3x so gathers from 3 k's are in
// flight simultaneously (hides L2 gather latency).
// ---------------------------------------------------------------------------
__global__ __launch_bounds__(256) void warp_apply_c(
    const ushort_t* __restrict__ Tc,    // (8,HW,32) bf16 c4-major
    const float* __restrict__ mask_ws,  // (2,9,HW)
    const float* __restrict__ off_ws,   // (2,72,HW)
    float* __restrict__ out)            // (4,64,9,HW)
{
    int bid = blockIdx.x;            // 8192
    int z  = bid & 7;
    int wc = (bid >> 3) & 3;
    int h  = bid >> 5;               // 0..255
    int c4 = threadIdx.x & 3;
    int pl = threadIdx.x >> 2;       // 0..63
    int w  = wc * 64 + pl;
    int pix = h * 256 + w;
    int xb = z >> 2, i = z & 3;

    const ushort_t* Tt = Tc + (size_t)z * HW * 32;

    float oxv[9], oyv[9], mv[9];
#pragma unroll
    for (int k = 0; k < 9; ++k) {
        oxv[k] = off_ws[(size_t)(z * 18 + 2 * k) * HW + pix];
        oyv[k] = off_ws[(size_t)(z * 18 + 2 * k + 1) * HW + pix];
        mv[k]  = mask_ws[(size_t)(xb * 9 + k) * HW + pix];
    }

    float* ob0 = out + ((size_t)(xb * 64 + i * 16 + c4 * 4)) * 9 * HW + pix;
    float* ob1 = ob0 + (size_t)128 * 9 * HW;
    int sec = c4 * 8;   // ushort offset of this lane's 16B sector

#pragma unroll 3
    for (int k = 0; k < 9; ++k) {
        float m = mv[k];
        float px = fminf(fmaxf((float)w + oxv[k], 0.f), 255.f);
        float py = fminf(fmaxf((float)h + oyv[k], 0.f), 255.f);
        float x0f = floorf(px), y0f = floorf(py);
        float wx = px - x0f, wy = py - y0f;
        int x0 = (int)x0f, y0 = (int)y0f;
        int x1 = min(x0 + 1, 255), y1 = min(y0 + 1, 255);

        float w00 = (1.f - wx) * (1.f - wy) * m;
        float w01 = wx * (1.f - wy) * m;
        float w10 = (1.f - wx) * wy * m;
        float w11 = wx * wy * m;

        uint4 A = *(const uint4*)(Tt + (size_t)(y0 * 256 + x0) * 32 + sec);
        uint4 B = *(const uint4*)(Tt + (size_t)(y0 * 256 + x1) * 32 + sec);
        uint4 C = *(const uint4*)(Tt + (size_t)(y1 * 256 + x0) * 32 + sec);
        uint4 D = *(const uint4*)(Tt + (size_t)(y1 * 256 + x1) * 32 + sec);

        float s0 = w00 * bflo(A.x), s1 = w00 * bfhi(A.x);
        float s2 = w00 * bflo(A.y), s3 = w00 * bfhi(A.y);
        float u0 = w00 * bflo(A.z), u1 = w00 * bfhi(A.z);
        float u2 = w00 * bflo(A.w), u3 = w00 * bfhi(A.w);

        s0 = fmaf(w01, bflo(B.x), s0); s1 = fmaf(w01, bfhi(B.x), s1);
        s2 = fmaf(w01, bflo(B.y), s2); s3 = fmaf(w01, bfhi(B.y), s3);
        u0 = fmaf(w01, bflo(B.z), u0); u1 = fmaf(w01, bfhi(B.z), u1);
        u2 = fmaf(w01, bflo(B.w), u2); u3 = fmaf(w01, bfhi(B.w), u3);

        s0 = fmaf(w10, bflo(C.x), s0); s1 = fmaf(w10, bfhi(C.x), s1);
        s2 = fmaf(w10, bflo(C.y), s2); s3 = fmaf(w10, bfhi(C.y), s3);
        u0 = fmaf(w10, bflo(C.z), u0); u1 = fmaf(w10, bfhi(C.z), u1);
        u2 = fmaf(w10, bflo(C.w), u2); u3 = fmaf(w10, bfhi(C.w), u3);

        s0 = fmaf(w11, bflo(D.x), s0); s1 = fmaf(w11, bfhi(D.x), s1);
        s2 = fmaf(w11, bflo(D.y), s2); s3 = fmaf(w11, bfhi(D.y), s3);
        u0 = fmaf(w11, bflo(D.z), u0); u1 = fmaf(w11, bfhi(D.z), u1);
        u2 = fmaf(w11, bflo(D.w), u2); u3 = fmaf(w11, bfhi(D.w), u3);

        float* p0 = ob0 + (size_t)k * HW;
        __builtin_nontemporal_store(s0, p0);
        __builtin_nontemporal_store(s1, p0 + (size_t)9 * HW);
        __builtin_nontemporal_store(s2, p0 + (size_t)18 * HW);
        __builtin_nontemporal_store(s3, p0 + (size_t)27 * HW);
        float* p1 = ob1 + (size_t)k * HW;
        __builtin_nontemporal_store(u0, p1);
        __builtin_nontemporal_store(u1, p1 + (size_t)9 * HW);
        __builtin_nontemporal_store(u2, p1 + (size_t)18 * HW);
        __builtin_nontemporal_store(u3, p1 + (size_t)27 * HW);
    }
}

// ---------------------------------------------------------------------------
// Fallback path (ws too small): LDS-weight conv to planes + direct warp.
// ---------------------------------------------------------------------------
__global__ __launch_bounds__(512) void conv_offsets_lds(
    const float* __restrict__ x, const float* __restrict__ WtP,
    const float* __restrict__ biasP,
    float* __restrict__ mask_ws, float* __restrict__ off_ws)
{
    __shared__ float wl[NFEAT * WROW + NOUT];
    int tid = threadIdx.x;
    for (int idx = tid; idx < NFEAT * WROW; idx += 512) wl[idx] = WtP[idx];
    if (tid < NOUT) wl[NFEAT * WROW + tid] = biasP[tid];
    __syncthreads();

    int gid = blockIdx.x * 512 + tid;
    int b = gid >> 16;
    int pix = gid & 65535;
    int h = pix >> 8, w = pix & 255;

    float acc[NOUT];
#pragma unroll
    for (int o = 0; o < NOUT; ++o) acc[o] = wl[NFEAT * WROW + o];

    const float* xb = x + (size_t)b * 64 * HW;
    for (int p = 0; p < 9; ++p) {
        int hh = h + p / 3 - 1;
        int ww = w + p % 3 - 1;
        bool valid = ((unsigned)hh < 256u) && ((unsigned)ww < 256u);
        int poff = hh * 256 + ww;
        for (int c = 0; c < 16; ++c) {
            float xv = valid ? xb[c * HW + poff] : 0.f;
            const float* wr = &wl[(p * 16 + c) * WROW];
#pragma unroll
            for (int o = 0; o < NOUT; ++o) acc[o] = fmaf(xv, wr[o], acc[o]);
        }
    }
    for (int c = 0; c < 48; ++c) {
        float xv = xb[(16 + c) * HW + pix];
        const float* wr = &wl[(144 + c) * WROW];
#pragma unroll
        for (int o = 0; o < NOUT; ++o) acc[o] = fmaf(xv, wr[o], acc[o]);
    }
#pragma unroll
    for (int k = 0; k < 9; ++k) mask_ws[(b * 9 + k) * HW + pix] = acc[k];
#pragma unroll
    for (int t = 0; t < 72; ++t) off_ws[(b * 72 + t) * HW + pix] = acc[9 + t];
}

__global__ __launch_bounds__(256) void warp_apply(
    const float* __restrict__ y,
    const float* __restrict__ mask_ws,
    const float* __restrict__ off_ws,
    float* __restrict__ out)
{
    int w = threadIdx.x;
    int h = blockIdx.x;
    int k = blockIdx.y;
    int z = blockIdx.z;
    int xb = z >> 2, i = z & 3;
    int pix = h * 256 + w;

    float ox = off_ws[(size_t)(z * 18 + 2 * k) * HW + pix];
    float oy = off_ws[(size_t)(z * 18 + 2 * k + 1) * HW + pix];
    float m  = mask_ws[(size_t)(xb * 9 + k) * HW + pix];

    float px = fminf(fmaxf((float)w + ox, 0.f), 255.f);
    float py = fminf(fmaxf((float)h + oy, 0.f), 255.f);
    float x0f = floorf(px), y0f = floorf(py);
    float wx = px - x0f, wy = py - y0f;
    int x0 = (int)x0f, y0 = (int)y0f;
    int x1 = min(x0 + 1, 255), y1 = min(y0 + 1, 255);

    float w00 = (1.f - wx) * (1.f - wy) * m;
    float w01 = wx * (1.f - wy) * m;
    float w10 = (1.f - wx) * wy * m;
    float w11 = wx * wy * m;

    int o00 = y0 * 256 + x0, o01 = y0 * 256 + x1;
    int o10 = y1 * 256 + x0, o11 = y1 * 256 + x1;

    const float* p1 = y + (size_t)(xb * 64 + i * 16) * HW;
    const float* p2 = y + (size_t)((xb + 2) * 64 + i * 16) * HW;
    float* out1 = out + ((size_t)(xb * 64 + i * 16) * 9 + k) * HW + pix;
    float* out2 = out + ((size_t)((xb + 2) * 64 + i * 16) * 9 + k) * HW + pix;

#pragma unroll
    for (int c = 0; c < 16; ++c) {
        const float* q = p1 + (size_t)c * HW;
        float v = w00 * q[o00] + w01 * q[o01] + w10 * q[o10] + w11 * q[o11];
        out1[(size_t)c * 9 * HW] = v;
        q = p2 + (size_t)c * HW;
        v = w00 * q[o00] + w01 * q[o01] + w10 * q[o10] + w11 * q[o11];
        out2[(size_t)c * 9 * HW] = v;
    }
}

// ---------------------------------------------------------------------------
extern "C" void kernel_launch(void* const* d_in, const int* in_sizes, int n_in,
                              void* d_out, int out_size, void* d_ws, size_t ws_size,
                              hipStream_t stream) {
    const float* x            = (const float*)d_in[0];
    const float* y            = (const float*)d_in[1];
    const float* off_pconv_w  = (const float*)d_in[2];
    const float* off_w        = (const float*)d_in[3];
    const float* off_b        = (const float*)d_in[4];
    const float* mask_pconv_w = (const float*)d_in[5];
    const float* mask_w       = (const float*)d_in[6];
    const float* mask_b       = (const float*)d_in[7];
    float* out = (float*)d_out;

    // ws: [WtP 192*84 f32 + biasP: 64KB] [mask (2,9,HW) f32: 4.7MB]
    //     [off (2,72,HW) f32: 37.7MB] [Tc (8,HW,32) bf16: 33.6MB]  ~76MB
    float* WtP     = (float*)d_ws;
    float* biasP   = WtP + NFEAT * WROW;
    float* mask_ws = (float*)((char*)d_ws + 65536);
    float* off_ws  = mask_ws + (size_t)2 * 9 * HW;
    ushort_t* Tc   = (ushort_t*)(off_ws + (size_t)2 * 72 * HW);
    size_t need = 65536 + (size_t)2 * 9 * HW * 4 + (size_t)2 * 72 * HW * 4
                + (size_t)8 * HW * 32 * 2;

    setup_weights<<<64, 256, 0, stream>>>(off_pconv_w, off_w, off_b,
                                          mask_pconv_w, mask_w, mask_b, WtP, biasP);

    if (ws_size >= need) {
        conv_and_transpose<<<2560, 256, 0, stream>>>(x, WtP, biasP, y,
                                                     mask_ws, off_ws, Tc);
        warp_apply_c<<<8192, 256, 0, stream>>>(Tc, mask_ws, off_ws, out);
    } else {
        conv_offsets_lds<<<256, 512, 0, stream>>>(x, WtP, biasP, mask_ws, off_ws);
        dim3 g2(256, 9, 8);
        warp_apply<<<g2, 256, 0, stream>>>(y, mask_ws, off_ws, out);
    }
}

// Round 14
// 295.020 us; speedup vs baseline: 1.1408x; 1.1408x over previous
//
#include <hip/hip_runtime.h>

#define HW 65536
#define NOUT 81     // 9 mask + 4*18 off
#define NFEAT 192   // 144 patch + 48 passthrough
#define WROW 84     // padded weight row stride

typedef unsigned short ushort_t;
typedef unsigned int uint_t;

__device__ __forceinline__ float bfhi(uint_t u) {   // high ushort IS the f32 pattern
    union { unsigned int i; float f; } v; v.i = u & 0xffff0000u; return v.f;
}
__device__ __forceinline__ float bflo(uint_t u) {
    union { unsigned int i; float f; } v; v.i = u << 16; return v.f;
}
__device__ __forceinline__ ushort_t f2bf(float f) {
    union { float f; unsigned int i; } v; v.f = f;
    unsigned int r = v.i + 0x7FFF + ((v.i >> 16) & 1);   // RNE
    return (ushort_t)(r >> 16);
}

// ---------------------------------------------------------------------------
// Setup: collapse (conv3x3 -> 1x1) into a single 192->81 linear map, padded.
// ---------------------------------------------------------------------------
__global__ __launch_bounds__(256) void setup_weights(
    const float* __restrict__ off_pconv_w,  // (4,16,16,3,3)
    const float* __restrict__ off_w,        // (4,18,64)
    const float* __restrict__ off_b,        // (4,18)
    const float* __restrict__ mask_pconv_w, // (16,16,3,3)
    const float* __restrict__ mask_w,       // (9,64)
    const float* __restrict__ mask_b,       // (9,)
    float* __restrict__ WtP,                // (192,84)
    float* __restrict__ biasP)              // (81,)
{
    int id = blockIdx.x * 256 + threadIdx.x;
    const float PTS[18] = {-1,-1, -1,0, -1,1, 0,-1, 0,0, 0,1, 1,-1, 1,0, 1,1};
    if (id < NFEAT * WROW) {
        int f = id / WROW;
        int o = id % WROW;
        float v = 0.f;
        if (o < NOUT) {
            if (f < 144) {
                int p = f >> 4, c = f & 15;
                float s = 0.f;
                if (o < 9) {
                    for (int cm = 0; cm < 16; ++cm)
                        s += mask_w[o * 64 + cm] * mask_pconv_w[(cm * 16 + c) * 9 + p];
                } else {
                    int oo = o - 9, i = oo / 18, j = oo % 18;
                    for (int cm = 0; cm < 16; ++cm)
                        s += off_w[(i * 18 + j) * 64 + cm] * off_pconv_w[((i * 16 + cm) * 16 + c) * 9 + p];
                }
                v = s;
            } else {
                int c = f - 144;
                if (o < 9) v = mask_w[o * 64 + 16 + c];
                else { int oo = o - 9, i = oo / 18, j = oo % 18; v = off_w[(i * 18 + j) * 64 + 16 + c]; }
            }
        }
        WtP[id] = v;
    } else if (id < NFEAT * WROW + NOUT) {
        int o = id - NFEAT * WROW;
        float v;
        if (o < 9) v = mask_b[o];
        else {
            int oo = o - 9, i = oo / 18, j = oo % 18;
            v = off_b[i * 18 + j] + PTS[j] * (float)(2 * i + 1);
        }
        biasP[o] = v;
    }
}

// ---------------------------------------------------------------------------
// Conv v3 (conv_sgpr): block = 64 pixels x 4 waves; each WAVE owns one
// 21-output slice (ob0 wave-uniform via readfirstlane) so weight loads are
// scalar (s_load -> SGPR) and FMAs read weights from SGPRs. No LDS at all;
// the weight stream moves off the LDS/vector-memory pipes entirely.
// ---------------------------------------------------------------------------
__global__ __launch_bounds__(256) void conv_sgpr(
    const float* __restrict__ x,     // (2,64,HW)
    const float* __restrict__ WtP,   // (192,84)
    const float* __restrict__ biasP, // (81,)
    float* __restrict__ mask_ws,     // (2,9,HW)
    float* __restrict__ off_ws)      // (2,72,HW)
{
    int tid = threadIdx.x;
    int lane = tid & 63;
    int bid = blockIdx.x;            // 2048 = b(2) x 1024 pixel-blocks
    int b = bid >> 10;
    int pixblk = (bid & 1023) * 64;
    int pix = pixblk + lane;
    int h = pix >> 8, w = pix & 255;

    // wave-uniform output-slice base (forces SGPR; all lanes of a wave equal)
    int ob0 = __builtin_amdgcn_readfirstlane((tid >> 6) * 20);

    float acc[21];
#pragma unroll
    for (int j = 0; j < 21; ++j) acc[j] = biasP[ob0 + j];   // uniform loads

    const float* xb = x + (size_t)b * 64 * HW;

    // 3x3 patch over channels 0..15 (zero padding)
#pragma unroll 1
    for (int p = 0; p < 9; ++p) {
        int hh = h + p / 3 - 1;          // uniform within wave (h uniform)
        int dx = p % 3 - 1;
        int ww = w + dx;
        bool valid = ((unsigned)hh < 256u) && ((unsigned)ww < 256u);
        int poff = hh * 256 + ww;
#pragma unroll 1
        for (int c = 0; c < 16; ++c) {
            float xv = valid ? xb[c * HW + poff] : 0.f;
            const float* wr = WtP + (p * 16 + c) * WROW + ob0;   // uniform addr
#pragma unroll
            for (int j = 0; j < 21; ++j) acc[j] = fmaf(xv, wr[j], acc[j]);
        }
    }
    // passthrough channels 16..63
#pragma unroll 1
    for (int c = 0; c < 48; ++c) {
        float xv = xb[(16 + c) * HW + pix];
        const float* wr = WtP + (144 + c) * WROW + ob0;          // uniform addr
#pragma unroll
        for (int j = 0; j < 21; ++j) acc[j] = fmaf(xv, wr[j], acc[j]);
    }

    // plane-layout stores, 64 consecutive pixels per instr
#pragma unroll
    for (int j = 0; j < 21; ++j) {
        int o = ob0 + j;
        float* pl;
        if (o < 9) pl = mask_ws + (size_t)(b * 9 + o) * HW + pix;
        else       pl = off_ws  + (size_t)(b * 72 + (o - 9)) * HW + pix;
        *pl = acc[j];
    }
}

// ---------------------------------------------------------------------------
// Transpose y -> c4-major interleaved Tc[z][pix][c4:{t0 4ch, t1 4ch}] bf16.
// (verbatim round 12)
// ---------------------------------------------------------------------------
__global__ __launch_bounds__(256) void transpose_y_c(
    const float* __restrict__ y, ushort_t* __restrict__ Tc)
{
    int bid = blockIdx.x;            // 2048
    int z = bid & 7, pr = bid >> 3;
    int pix = pr * 256 + threadIdx.x;
    int xb = z >> 2, i = z & 3;

    const float* p0 = y + (size_t)(xb * 64 + i * 16) * HW + pix;
    const float* p1 = y + (size_t)((xb + 2) * 64 + i * 16) * HW + pix;

    ushort_t v0[16], v1[16];
#pragma unroll
    for (int c = 0; c < 16; ++c) v0[c] = f2bf(p0[(size_t)c * HW]);
#pragma unroll
    for (int c = 0; c < 16; ++c) v1[c] = f2bf(p1[(size_t)c * HW]);

    uint4* dst = (uint4*)(Tc + ((size_t)z * HW + pix) * 32);
#pragma unroll
    for (int j = 0; j < 4; ++j) {
        ushort_t row[8] = {v0[4*j], v0[4*j+1], v0[4*j+2], v0[4*j+3],
                           v1[4*j], v1[4*j+1], v1[4*j+2], v1[4*j+3]};
        dst[j] = *(const uint4*)row;
    }
}

// ---------------------------------------------------------------------------
// Warp kernel v7 (verbatim round 12, unroll 1 — the 178us best-measured).
// ---------------------------------------------------------------------------
__global__ __launch_bounds__(256) void warp_apply_c(
    const ushort_t* __restrict__ Tc,    // (8,HW,32) bf16 c4-major
    const float* __restrict__ mask_ws,  // (2,9,HW)
    const float* __restrict__ off_ws,   // (2,72,HW)
    float* __restrict__ out)            // (4,64,9,HW)
{
    int bid = blockIdx.x;            // 8192
    int z  = bid & 7;
    int wc = (bid >> 3) & 3;
    int h  = bid >> 5;               // 0..255
    int c4 = threadIdx.x & 3;
    int pl = threadIdx.x >> 2;       // 0..63
    int w  = wc * 64 + pl;
    int pix = h * 256 + w;
    int xb = z >> 2, i = z & 3;

    const ushort_t* Tt = Tc + (size_t)z * HW * 32;

    float oxv[9], oyv[9], mv[9];
#pragma unroll
    for (int k = 0; k < 9; ++k) {
        oxv[k] = off_ws[(size_t)(z * 18 + 2 * k) * HW + pix];
        oyv[k] = off_ws[(size_t)(z * 18 + 2 * k + 1) * HW + pix];
        mv[k]  = mask_ws[(size_t)(xb * 9 + k) * HW + pix];
    }

    float* ob0 = out + ((size_t)(xb * 64 + i * 16 + c4 * 4)) * 9 * HW + pix;
    float* ob1 = ob0 + (size_t)128 * 9 * HW;
    int sec = c4 * 8;   // ushort offset of this lane's 16B sector

#pragma unroll 1
    for (int k = 0; k < 9; ++k) {
        float m = mv[k];
        float px = fminf(fmaxf((float)w + oxv[k], 0.f), 255.f);
        float py = fminf(fmaxf((float)h + oyv[k], 0.f), 255.f);
        float x0f = floorf(px), y0f = floorf(py);
        float wx = px - x0f, wy = py - y0f;
        int x0 = (int)x0f, y0 = (int)y0f;
        int x1 = min(x0 + 1, 255), y1 = min(y0 + 1, 255);

        float w00 = (1.f - wx) * (1.f - wy) * m;
        float w01 = wx * (1.f - wy) * m;
        float w10 = (1.f - wx) * wy * m;
        float w11 = wx * wy * m;

        uint4 A = *(const uint4*)(Tt + (size_t)(y0 * 256 + x0) * 32 + sec);
        uint4 B = *(const uint4*)(Tt + (size_t)(y0 * 256 + x1) * 32 + sec);
        uint4 C = *(const uint4*)(Tt + (size_t)(y1 * 256 + x0) * 32 + sec);
        uint4 D = *(const uint4*)(Tt + (size_t)(y1 * 256 + x1) * 32 + sec);

        float s0 = w00 * bflo(A.x), s1 = w00 * bfhi(A.x);
        float s2 = w00 * bflo(A.y), s3 = w00 * bfhi(A.y);
        float u0 = w00 * bflo(A.z), u1 = w00 * bfhi(A.z);
        float u2 = w00 * bflo(A.w), u3 = w00 * bfhi(A.w);

        s0 = fmaf(w01, bflo(B.x), s0); s1 = fmaf(w01, bfhi(B.x), s1);
        s2 = fmaf(w01, bflo(B.y), s2); s3 = fmaf(w01, bfhi(B.y), s3);
        u0 = fmaf(w01, bflo(B.z), u0); u1 = fmaf(w01, bfhi(B.z), u1);
        u2 = fmaf(w01, bflo(B.w), u2); u3 = fmaf(w01, bfhi(B.w), u3);

        s0 = fmaf(w10, bflo(C.x), s0); s1 = fmaf(w10, bfhi(C.x), s1);
        s2 = fmaf(w10, bflo(C.y), s2); s3 = fmaf(w10, bfhi(C.y), s3);
        u0 = fmaf(w10, bflo(C.z), u0); u1 = fmaf(w10, bfhi(C.z), u1);
        u2 = fmaf(w10, bflo(C.w), u2); u3 = fmaf(w10, bfhi(C.w), u3);

        s0 = fmaf(w11, bflo(D.x), s0); s1 = fmaf(w11, bfhi(D.x), s1);
        s2 = fmaf(w11, bflo(D.y), s2); s3 = fmaf(w11, bfhi(D.y), s3);
        u0 = fmaf(w11, bflo(D.z), u0); u1 = fmaf(w11, bfhi(D.z), u1);
        u2 = fmaf(w11, bflo(D.w), u2); u3 = fmaf(w11, bfhi(D.w), u3);

        float* p0 = ob0 + (size_t)k * HW;
        __builtin_nontemporal_store(s0, p0);
        __builtin_nontemporal_store(s1, p0 + (size_t)9 * HW);
        __builtin_nontemporal_store(s2, p0 + (size_t)18 * HW);
        __builtin_nontemporal_store(s3, p0 + (size_t)27 * HW);
        float* p1 = ob1 + (size_t)k * HW;
        __builtin_nontemporal_store(u0, p1);
        __builtin_nontemporal_store(u1, p1 + (size_t)9 * HW);
        __builtin_nontemporal_store(u2, p1 + (size_t)18 * HW);
        __builtin_nontemporal_store(u3, p1 + (size_t)27 * HW);
    }
}

// ---------------------------------------------------------------------------
// Fallback path (ws too small): conv_sgpr writes planes + direct warp.
// ---------------------------------------------------------------------------
__global__ __launch_bounds__(256) void warp_apply(
    const float* __restrict__ y,
    const float* __restrict__ mask_ws,
    const float* __restrict__ off_ws,
    float* __restrict__ out)
{
    int w = threadIdx.x;
    int h = blockIdx.x;
    int k = blockIdx.y;
    int z = blockIdx.z;
    int xb = z >> 2, i = z & 3;
    int pix = h * 256 + w;

    float ox = off_ws[(size_t)(z * 18 + 2 * k) * HW + pix];
    float oy = off_ws[(size_t)(z * 18 + 2 * k + 1) * HW + pix];
    float m  = mask_ws[(size_t)(xb * 9 + k) * HW + pix];

    float px = fminf(fmaxf((float)w + ox, 0.f), 255.f);
    float py = fminf(fmaxf((float)h + oy, 0.f), 255.f);
    float x0f = floorf(px), y0f = floorf(py);
    float wx = px - x0f, wy = py - y0f;
    int x0 = (int)x0f, y0 = (int)y0f;
    int x1 = min(x0 + 1, 255), y1 = min(y0 + 1, 255);

    float w00 = (1.f - wx) * (1.f - wy) * m;
    float w01 = wx * (1.f - wy) * m;
    float w10 = (1.f - wx) * wy * m;
    float w11 = wx * wy * m;

    int o00 = y0 * 256 + x0, o01 = y0 * 256 + x1;
    int o10 = y1 * 256 + x0, o11 = y1 * 256 + x1;

    const float* p1 = y + (size_t)(xb * 64 + i * 16) * HW;
    const float* p2 = y + (size_t)((xb + 2) * 64 + i * 16) * HW;
    float* out1 = out + ((size_t)(xb * 64 + i * 16) * 9 + k) * HW + pix;
    float* out2 = out + ((size_t)((xb + 2) * 64 + i * 16) * 9 + k) * HW + pix;

#pragma unroll
    for (int c = 0; c < 16; ++c) {
        const float* q = p1 + (size_t)c * HW;
        float v = w00 * q[o00] + w01 * q[o01] + w10 * q[o10] + w11 * q[o11];
        out1[(size_t)c * 9 * HW] = v;
        q = p2 + (size_t)c * HW;
        v = w00 * q[o00] + w01 * q[o01] + w10 * q[o10] + w11 * q[o11];
        out2[(size_t)c * 9 * HW] = v;
    }
}

// ---------------------------------------------------------------------------
extern "C" void kernel_launch(void* const* d_in, const int* in_sizes, int n_in,
                              void* d_out, int out_size, void* d_ws, size_t ws_size,
                              hipStream_t stream) {
    const float* x            = (const float*)d_in[0];
    const float* y            = (const float*)d_in[1];
    const float* off_pconv_w  = (const float*)d_in[2];
    const float* off_w        = (const float*)d_in[3];
    const float* off_b        = (const float*)d_in[4];
    const float* mask_pconv_w = (const float*)d_in[5];
    const float* mask_w       = (const float*)d_in[6];
    const float* mask_b       = (const float*)d_in[7];
    float* out = (float*)d_out;

    // ws: [WtP 192*84 f32 + biasP: 64KB] [mask (2,9,HW) f32: 4.7MB]
    //     [off (2,72,HW) f32: 37.7MB] [Tc (8,HW,32) bf16: 33.6MB]  ~76MB
    float* WtP     = (float*)d_ws;
    float* biasP   = WtP + NFEAT * WROW;
    float* mask_ws = (float*)((char*)d_ws + 65536);
    float* off_ws  = mask_ws + (size_t)2 * 9 * HW;
    ushort_t* Tc   = (ushort_t*)(off_ws + (size_t)2 * 72 * HW);
    size_t need = 65536 + (size_t)2 * 9 * HW * 4 + (size_t)2 * 72 * HW * 4
                + (size_t)8 * HW * 32 * 2;

    setup_weights<<<64, 256, 0, stream>>>(off_pconv_w, off_w, off_b,
                                          mask_pconv_w, mask_w, mask_b, WtP, biasP);

    conv_sgpr<<<2048, 256, 0, stream>>>(x, WtP, biasP, mask_ws, off_ws);

    if (ws_size >= need) {
        transpose_y_c<<<2048, 256, 0, stream>>>(y, Tc);
        warp_apply_c<<<8192, 256, 0, stream>>>(Tc, mask_ws, off_ws, out);
    } else {
        dim3 g2(256, 9, 8);
        warp_apply<<<g2, 256, 0, stream>>>(y, mask_ws, off_ws, out);
    }
}